// Round 3
// baseline (256.941 us; speedup 1.0000x reference)
//
#include <hip/hip_runtime.h>
#include <cmath>

// Problem constants from the reference: x is (16, 1, 1536, 1536) float32.
#define B_ 16
#define H_ 1536
#define W_ 1536

typedef float v4f __attribute__((ext_vector_type(4)));

// NUMERICS CONTRACT (v4 -- identical numerics to v3, restructured data
// movement): the sign of disc = Hc^2 - Kc is rounding-determined and
// selects between si=0 (NaN path) and si~=+-1. Reference association and
// rounding are reproduced EXACTLY wherever that sign is in doubt.
//  * FRONT-END (p,q,r,s,t,one_pq,A,numk): contract(off), reference order.
//  * FAST PATH: r1 = rsq(one_pq); Hc = (-0.5*A)*r1^3; Kc = numk*r1^4.
//    |disc_fast - disc_ieee| <= ~2^-20 * (Hc^2+|Kc|).
//  * GUARD: lanes with |disc_fast| <= 2^-16 * (Hc^2+|Kc|) (16x margin)
//    recomputed with IEEE div/sqrt in reference association -> disc SIGN
//    always matches the reference bitwise. Unflagged lanes: si error
//    < 1e-4 (smooth/saturating atan region).
//  * TAIL: z = Hc/root; atan via u = mn/mx of (|Hc|, root), sign from Hc;
//    cndmask (not min/max) so NaN root -> u=NaN -> si=0 (reference
//    remove_nan cascade). root = raw v_sqrt for all lanes (sign of disc
//    already exact; ~ulp root error moves si by ~1e-7).
//  * remove_nan(Hc/Kc) dropped: one_pq >= 1 -> finite. (see v3 notes)
//
// STRUCTURE (v4): each block computes a 4-row band; each thread computes
// 4 elems x 4 rows. 6 row-chunk dwordx4 loads + 9 edge scalars issue up
// front -> ~15 independent loads in flight per wave (vs 6 at VGPR=24 in
// v3, which left the kernel memory-LATENCY bound at ~3.5 TB/s effective).
// Loads/stores stay perfectly unit-stride coalesced. Vertical register
// reuse also halves per-element L1 traffic and tightens HBM fetch toward
// the 151 MB ideal (block reads 6 rows for 4 written rows; adjacent bands
// share 2 rows via L2 on the same XCD thanks to the band swizzle).
__global__ __launch_bounds__(384) void ShapeIndex_kernel(
        const float* __restrict__ x, float* __restrict__ out) {
#pragma clang fp contract(off)
    // XCD-chunked band swizzle: grid.x=384 bands (divisible by 8 XCDs);
    // XCD k walks bands [48k, 48k+48) = rows [192k, 192k+192) contiguous.
    const int graw = blockIdx.x;
    const int g  = (graw & 7) * (384 / 8) + (graw >> 3);   // bijective
    const int h0 = g * 4;                                  // band top row
    const int b  = blockIdx.y;                             // 0..15
    const int w  = threadIdx.x * 4;                        // 0..1532

    const float* plane = x + (size_t)b * (H_ * W_);
    const int rm1 = (h0 == 0) ? H_ - 1 : h0 - 1;
    const int rm2 = (h0 == 0) ? H_ - 2 : h0 - 2;

    // rows[i], i=0..5 -> h0-2, h0-1, h0, h0+1, h0+2, h0+3 (wrapped)
    const int rows[6] = {rm2, rm1, h0, h0 + 1, h0 + 2, h0 + 3};

    // ---- all loads issue up front (independent -> deep MLP) ----
    float4 R[6];
#pragma unroll
    for (int i = 0; i < 6; ++i)
        R[i] = *(const float4*)(plane + (size_t)rows[i] * W_ + w);

    const int wm1 = (w == 0) ? (W_ - 1) : (w - 1);
    const int wm2 = (w == 0) ? (W_ - 2) : (w - 2);
    float Lw1[6], Lw2[6];
#pragma unroll
    for (int i = 1; i < 6; ++i) Lw1[i] = plane[(size_t)rows[i] * W_ + wm1];
#pragma unroll
    for (int i = 2; i < 6; ++i) Lw2[i] = plane[(size_t)rows[i] * W_ + wm2];

    float* const oplane = out + (size_t)b * (H_ * W_);

#pragma unroll
    for (int rr = 0; rr < 4; ++rr) {
        const float4 vc = R[2 + rr];     // x[h][w..w+3]
        const float4 v1 = R[1 + rr];     // x[h-1][...]
        const float4 v2 = R[0 + rr];     // x[h-2][...]
        const float L0  = Lw1[2 + rr];   // x[h][w-1]
        const float L1  = Lw2[2 + rr];   // x[h][w-2]
        const float Lh1 = Lw1[1 + rr];   // x[h-1][w-1]

        const v4f xc    = {vc.x, vc.y, vc.z, vc.w};
        const v4f xh1   = {v1.x, v1.y, v1.z, v1.w};
        const v4f xh2   = {v2.x, v2.y, v2.z, v2.w};
        const v4f xw1   = {L0,  vc.x, vc.y, vc.z};   // x[h][w-1]
        const v4f xw2   = {L1,  L0,  vc.x, vc.y};    // x[h][w-2]
        const v4f xh1w1 = {Lh1, v1.x, v1.y, v1.z};   // x[h-1][w-1]

        // grad(m, ax) = roll(m,1,ax) - m : single f32 subs, reference order.
        const v4f p    = xh1   - xc;
        const v4f q    = xw1   - xc;
        const v4f p_up = xh2   - xh1;
        const v4f p_lf = xh1w1 - xw1;
        const v4f q_lf = xw2   - xw1;
        const v4f r = p_up - p;
        const v4f s = p_lf - p;
        const v4f t = q_lf - q;

        const v4f pp = p * p;
        const v4f qq = q * q;
        const v4f one_pq = (1.0f + pp) + qq;           // (1.0 + p*p) + q*q
        // ((1+q*q)*r - 2.0*p*q*s) + (1+p*p)*t, left-to-right like Python
        const v4f A = ((1.0f + qq) * r - ((2.0f * p) * q) * s) + (1.0f + pp) * t;
        const v4f numk = r * t - s * s;

        // ---- FAST PATH: one rsq; powers give both denominators.
        v4f rsqv;
#pragma unroll
        for (int j = 0; j < 4; ++j)
            rsqv[j] = __builtin_amdgcn_rsqf(one_pq[j]);  // one_pq^-1/2
        const v4f i2 = rsqv * rsqv;                      // ~ one_pq^-1
        const v4f i3 = i2 * rsqv;                        // ~ one_pq^-3/2
        const v4f i4 = i2 * i2;                          // ~ one_pq^-2
        const v4f halfA = -0.5f * A;
        v4f Hc = halfA * i3;                             // ~ -A/(2*sqrt(cube))
        v4f Kc = numk * i4;                              // ~ numk/sq
        const v4f HH = Hc * Hc;
        v4f disc = HH - Kc;                              // sign is critical

        // ---- GUARD: route sign-ambiguous lanes to the bitwise-exact path.
        v4f mag;
#pragma unroll
        for (int j = 0; j < 4; ++j) mag[j] = HH[j] + __builtin_fabsf(Kc[j]);
        const v4f thr = mag * 0x1p-16f;
        bool need[4];
        bool any = false;
#pragma unroll
        for (int j = 0; j < 4; ++j) {
            need[j] = __builtin_fabsf(disc[j]) <= thr[j];  // mag==0 -> flagged
            any |= need[j];
        }
        if (__builtin_expect(any, 0)) {
#pragma unroll
            for (int j = 0; j < 4; ++j) if (need[j]) {
                // Exact reference association: IEEE sqrt + IEEE div.
                const float sqj  = one_pq[j] * one_pq[j];      // one_pq ** 2
                const float cubj = sqj * one_pq[j];            // one_pq ** 3
                const float se  = __builtin_sqrtf(cubj);       // IEEE 0.5ulp
                const float hce = -(A[j] / (2.0f * se));       // IEEE div
                const float kce = numk[j] / sqj;               // IEEE div
                Hc[j]   = hce;
                disc[j] = hce * hce - kce;                     // bitwise ref
            }
        }

        // root: raw sqrt -- disc sign already exact; disc<0 -> NaN.
        v4f root;
#pragma unroll
        for (int j = 0; j < 4; ++j) root[j] = __builtin_amdgcn_sqrtf(disc[j]);

        // atan argument u = mn/mx of (|Hc|, root); sign carried by Hc.
        // cndmask (not min/max) so NaN root -> mx=NaN -> u=NaN -> si=0.
        v4f u;
        bool big[4];
#pragma unroll
        for (int j = 0; j < 4; ++j) {
            const float aH = __builtin_fabsf(Hc[j]);
            big[j] = aH > root[j];                  // NaN compares false
            const float mn = big[j] ? root[j] : aH;
            const float mx = big[j] ? aH : root[j];
            u[j] = mn * __builtin_amdgcn_rcpf(mx);  // mx=0 -> NaN (ref: 0/0)
        }

        // fast atan, ~1e-5 rad: atan(x)=pi/2-atan(1/x) for the big branch.
        const v4f x2 = u * u;
        const v4f C5 = -0.01172120f, C4 = 0.05265332f, C3 = -0.11643287f,
                  C2 = 0.19354346f,  C1 = -0.33262347f, C0 = 0.99997726f;
        v4f pl = __builtin_elementwise_fma(x2, C5, C4);
        pl = __builtin_elementwise_fma(x2, pl, C3);
        pl = __builtin_elementwise_fma(x2, pl, C2);
        pl = __builtin_elementwise_fma(x2, pl, C1);
        pl = __builtin_elementwise_fma(x2, pl, C0);
        const v4f a    = u * pl;
        const v4f asub = 1.57079632679489662f - a;

        v4f rs;
#pragma unroll
        for (int j = 0; j < 4; ++j)
            rs[j] = __builtin_copysignf(big[j] ? asub[j] : a[j], Hc[j]);
        const v4f siv = 0.63661977236758134f * rs;

        float res[4];
#pragma unroll
        for (int j = 0; j < 4; ++j)
            res[j] = (siv[j] == siv[j]) ? siv[j] : 0.0f;   // remove_nan

        *(float4*)(oplane + (size_t)(h0 + rr) * W_ + w) =
            make_float4(res[0], res[1], res[2], res[3]);
    }
}

extern "C" void kernel_launch(void* const* d_in, const int* in_sizes, int n_in,
                              void* d_out, int out_size, void* d_ws, size_t ws_size,
                              hipStream_t stream) {
    const float* x = (const float*)d_in[0];
    float* out = (float*)d_out;
    dim3 grid(H_ / 4, B_);   // 384 four-row bands x 16 batches
    dim3 block(384);
    ShapeIndex_kernel<<<grid, block, 0, stream>>>(x, out);
}